// Round 2
// baseline (294.975 us; speedup 1.0000x reference)
//
#include <hip/hip_runtime.h>

#define DD 512
#define AA 128
#define BB 1024

// Pass 1: per-block partial column sums of attribute [BB, DD].
// grid 128 blocks x 256 threads; block b sums rows b*8 .. b*8+7 into partial[b][512].
__global__ void k_partial(const float* __restrict__ attr, float* __restrict__ partial) {
    const int r0 = blockIdx.x * 8;
    const int t  = threadIdx.x;
    float s0 = 0.0f, s1 = 0.0f;
    #pragma unroll
    for (int r = 0; r < 8; ++r) {
        const float* row = attr + (size_t)(r0 + r) * DD;
        s0 += row[t];
        s1 += row[t + 256];
    }
    float* dst = partial + (size_t)blockIdx.x * DD;
    dst[t]       = s0;
    dst[t + 256] = s1;
}

// Pass 2: reduce 128 partials -> colsum[512]. One block, 512 threads, coalesced.
__global__ void k_reduce(const float* __restrict__ partial, float* __restrict__ colsum) {
    const int t = threadIdx.x;
    float s = 0.0f;
    #pragma unroll 8
    for (int i = 0; i < 128; ++i) s += partial[(size_t)i * DD + t];
    colsum[t] = s;
}

// vout[d] = scale * sum_e vin[e]*W[d*DD+e] + bias[d]
// one wave per output row; grid 128 blocks x 256 threads (4 waves)
__global__ void k_gemv(const float* __restrict__ W, const float* __restrict__ bias,
                       const float* __restrict__ vin, float* __restrict__ vout,
                       float scale) {
    const int wave = threadIdx.x >> 6;        // 0..3
    const int lane = threadIdx.x & 63;
    const int d = blockIdx.x * 4 + wave;      // 0..511
    const float* wr = W + (size_t)d * DD;
    float s = 0.0f;
    #pragma unroll
    for (int e = lane; e < DD; e += 64) s += vin[e] * wr[e];
    #pragma unroll
    for (int off = 32; off > 0; off >>= 1) s += __shfl_down(s, off, 64);
    if (lane == 0) vout[d] = s * scale + bias[d];
}

// broadcast o[512] to out [BB*AA*DD]; each thread's source float4 is loop-invariant
// (grid stride 524288 is a multiple of 128 float4 per row-vector).
__global__ void k_bcast(const float* __restrict__ o, float4* __restrict__ out, long total4) {
    long idx = (long)blockIdx.x * blockDim.x + threadIdx.x;
    const long step = (long)gridDim.x * blockDim.x;   // 2048*256 = 524288
    const float4 v = ((const float4*)o)[idx & 127];   // constant per thread
    for (; idx < total4; idx += step) out[idx] = v;
}

extern "C" void kernel_launch(void* const* d_in, const int* in_sizes, int n_in,
                              void* d_out, int out_size, void* d_ws, size_t ws_size,
                              hipStream_t stream) {
    // setup_inputs order: attribute, prompt, Wq, bq, Wk, bk, Wv, bv, Wo, bo
    const float* attr = (const float*)d_in[0];
    const float* Wv   = (const float*)d_in[6];
    const float* bv   = (const float*)d_in[7];
    const float* Wo   = (const float*)d_in[8];
    const float* bo   = (const float*)d_in[9];

    float* ws      = (float*)d_ws;
    float* partial = ws;                 // [128*512]
    float* colsum  = ws + 128 * DD;      // [512]
    float* vbar    = colsum + DD;        // [512]
    float* ovec    = vbar + DD;          // [512]
    float* out     = (float*)d_out;

    k_partial<<<128, 256, 0, stream>>>(attr, partial);
    k_reduce <<<1, 512, 0, stream>>>(partial, colsum);
    k_gemv   <<<128, 256, 0, stream>>>(Wv, bv, colsum, vbar, 1.0f / (float)BB);
    k_gemv   <<<128, 256, 0, stream>>>(Wo, bo, vbar, ovec, 1.0f);

    const long total4 = (long)BB * AA * (DD / 4);     // 16,777,216 float4
    k_bcast  <<<2048, 256, 0, stream>>>(ovec, (float4*)out, total4);
}